// Round 8
// baseline (193.110 us; speedup 1.0000x reference)
//
#include <hip/hip_runtime.h>
#include <math.h>

// Problem constants
#define B_  2
#define S_  2048
#define E_  768
#define H_  12
#define HD_ 64
#define M_  (B_ * S_)     // 4096 rows
#define N3E (3 * E_)      // 2304

typedef __attribute__((ext_vector_type(8)))  short short8;      // 8 bf16
typedef __attribute__((ext_vector_type(8)))  _Float16 half8;    // 8 fp16
typedef __attribute__((ext_vector_type(4)))  _Float16 half4;
typedef __attribute__((ext_vector_type(2)))  _Float16 half2_t;
typedef __attribute__((ext_vector_type(4)))  float floatx4;     // 16x16 MFMA C/D
typedef __attribute__((ext_vector_type(16))) float floatx16;    // 32x32 MFMA C/D

// fold 1/sqrt(64) * log2(e) into q so softmax is a bare v_exp_f32 (exp2)
#define QSCALE 0.18033688011112042f

// round-to-nearest-even fp32 -> bf16
__device__ inline unsigned short f2bf(float f) {
  union { float f; unsigned u; } a; a.f = f;
  unsigned r = a.u + 0x7fff + ((a.u >> 16) & 1);
  return (unsigned short)(r >> 16);
}
// round-half-up (2 VALU ops; still <= 0.5 ulp)
__device__ inline unsigned short f2bf_fast(float f) {
  union { float f; unsigned u; } a; a.f = f;
  return (unsigned short)((a.u + 0x8000u) >> 16);
}
// packed fp32x2 -> fp16x2 (single v_cvt_pkrtz_f16_f32)
__device__ inline half2_t pkrtz(float a, float b) {
  return __builtin_bit_cast(half2_t, __builtin_amdgcn_cvt_pkrtz(a, b));
}

// ---------------------------------------------------------------------------
// Kernel 0: fp32 -> bf16 weight conversion
// ---------------------------------------------------------------------------
__global__ __launch_bounds__(256) void cvt_kernel(
    const float* __restrict__ src, unsigned short* __restrict__ dst, int n4) {
  int i = blockIdx.x * 256 + threadIdx.x;
  if (i < n4) {
    float4 f = *(const float4*)&src[i * 4];
    ushort4 r;
    r.x = f2bf(f.x); r.y = f2bf(f.y); r.z = f2bf(f.z); r.w = f2bf(f.w);
    *(ushort4*)&dst[i * 4] = r;
  }
}

// ---------------------------------------------------------------------------
// Kernel 1: LayerNorm -> bf16 xn
// ---------------------------------------------------------------------------
__global__ __launch_bounds__(256) void ln_kernel(
    const float* __restrict__ x, const float* __restrict__ gamma,
    const float* __restrict__ beta, unsigned short* __restrict__ xnb) {
  const int row = blockIdx.x;
  const int t = threadIdx.x;
  const float* xr = x + (size_t)row * E_;

  float v0 = xr[t];
  float v1 = xr[t + 256];
  float v2 = xr[t + 512];
  float s  = v0 + v1 + v2;
  float s2 = v0 * v0 + v1 * v1 + v2 * v2;

  for (int o = 32; o > 0; o >>= 1) {
    s  += __shfl_down(s, o);
    s2 += __shfl_down(s2, o);
  }
  __shared__ float red[8];
  const int wave = t >> 6, lane = t & 63;
  if (lane == 0) { red[wave] = s; red[4 + wave] = s2; }
  __syncthreads();
  s  = red[0] + red[1] + red[2] + red[3];
  s2 = red[4] + red[5] + red[6] + red[7];

  const float mu  = s * (1.0f / E_);
  const float var = s2 * (1.0f / E_) - mu * mu;
  const float rs  = rsqrtf(var + 1e-5f);

  unsigned short* xo = xnb + (size_t)row * E_;
  xo[t]       = f2bf((v0 - mu) * rs * gamma[t]       + beta[t]);
  xo[t + 256] = f2bf((v1 - mu) * rs * gamma[t + 256] + beta[t + 256]);
  xo[t + 512] = f2bf((v2 - mu) * rs * gamma[t + 512] + beta[t + 512]);
}

// ---------------------------------------------------------------------------
// Kernel 2/4: bf16 MFMA GEMM  C[M][N] = A[M][768] * W[N][768]^T + bias[N]
// mode 0 epilogue emits q/k (bf16) and v (fp16) in MFMA-fragment-swizzled
// layouts so attention fragment loads are base + lane*8 (fully coalesced):
//   q/k: [bh][tb64][half][kc][lane][8]   (q pre-scaled by QSCALE)
//   v:   [bh][tb64][half][db][kc2][lane][8]  (fp16)
// mode 1: fp32 out[M][768] = C + bias
// ---------------------------------------------------------------------------
__global__ __launch_bounds__(256) void bgemm_kernel(
    const unsigned short* __restrict__ A, const unsigned short* __restrict__ Wb,
    const float* __restrict__ bias, int mode,
    unsigned short* __restrict__ qbf, unsigned short* __restrict__ kbf,
    _Float16* __restrict__ vth, float* __restrict__ out) {
  __shared__ __align__(16) unsigned short As[128 * 64];
  __shared__ __align__(16) unsigned short Bs[128 * 64];

  const int t  = threadIdx.x;
  const int ln = t & 63, wv = t >> 6;
  const int lr = ln & 15, lg = ln >> 4;
  const int wr = wv >> 1, wc = wv & 1;
  const int m0 = blockIdx.x * 128, n0 = blockIdx.y * 128;

  const int srow = ln >> 3;
  const int scol = (ln & 7) * 8;

  const unsigned short* Ag = A  + (size_t)(m0 + wv * 32 + srow) * 768 + scol;
  const unsigned short* Bg = Wb + (size_t)(n0 + wv * 32 + srow) * 768 + scol;

  floatx4 acc[4][4];
#pragma unroll
  for (int i = 0; i < 4; i++)
#pragma unroll
    for (int j = 0; j < 4; j++) acc[i][j] = (floatx4){0.f, 0.f, 0.f, 0.f};

  for (int k0 = 0; k0 < 768; k0 += 64) {
    __syncthreads();
#pragma unroll
    for (int j = 0; j < 4; j++) {
      __builtin_amdgcn_global_load_lds(
          (const __attribute__((address_space(1))) void*)(Ag + k0 + j * 8 * 768),
          (__attribute__((address_space(3))) void*)(&As[(wv * 32 + j * 8) * 64]),
          16, 0, 0);
      __builtin_amdgcn_global_load_lds(
          (const __attribute__((address_space(1))) void*)(Bg + k0 + j * 8 * 768),
          (__attribute__((address_space(3))) void*)(&Bs[(wv * 32 + j * 8) * 64]),
          16, 0, 0);
    }
    __syncthreads();

#pragma unroll
    for (int kk = 0; kk < 2; kk++) {
      short8 af[4], bf[4];
#pragma unroll
      for (int i = 0; i < 4; i++)
        af[i] = *(const short8*)&As[(wr * 64 + i * 16 + lr) * 64 + kk * 32 + lg * 8];
#pragma unroll
      for (int j = 0; j < 4; j++)
        bf[j] = *(const short8*)&Bs[(wc * 64 + j * 16 + lr) * 64 + kk * 32 + lg * 8];
#pragma unroll
      for (int i = 0; i < 4; i++)
#pragma unroll
        for (int j = 0; j < 4; j++)
          acc[i][j] = __builtin_amdgcn_mfma_f32_16x16x32_bf16(af[i], bf[j], acc[i][j], 0, 0, 0);
    }
  }

  if (mode == 1) {
#pragma unroll
    for (int i = 0; i < 4; i++) {
      const int grow0 = m0 + wr * 64 + i * 16 + lg * 4;
#pragma unroll
      for (int j = 0; j < 4; j++) {
        const int gcol = n0 + wc * 64 + j * 16 + lr;
        const float bb = bias[gcol];
#pragma unroll
        for (int r = 0; r < 4; r++)
          out[(size_t)(grow0 + r) * E_ + gcol] = acc[i][j][r] + bb;
      }
    }
  } else {
#pragma unroll
    for (int i = 0; i < 4; i++) {
      const int grow0 = m0 + wr * 64 + i * 16 + lg * 4;
      const int bq = grow0 >> 11, s0 = grow0 & 2047;
      const int tb = s0 >> 6, kh = (s0 >> 5) & 1;
#pragma unroll
      for (int j = 0; j < 4; j++) {
        const int n = n0 + wc * 64 + j * 16 + lr;
        const int h = n / 192, w = (n >> 6) % 3, d = n & 63;
        const int bh = bq * H_ + h;
        const float bb = bias[n];
        if (w == 2) {
          // V fragment layout (fp16): rows = keys s0..s0+3 -> e0..e0+3
          const int db = d >> 5, l31v = d & 31;
          const int kc2 = (s0 >> 4) & 1, l5v = (s0 >> 3) & 1, e0 = s0 & 7;
          half2_t h01 = pkrtz(acc[i][j][0] + bb, acc[i][j][1] + bb);
          half2_t h23 = pkrtz(acc[i][j][2] + bb, acc[i][j][3] + bb);
          half4 hv = __builtin_shufflevector(h01, h23, 0, 1, 2, 3);
          const size_t idx =
              ((((((size_t)bh * 32 + tb) * 2 + kh) * 2 + db) * 2 + kc2) * 2 + l5v) * 256
              + (size_t)l31v * 8 + e0;
          *(half4*)&vth[idx] = hv;
        } else {
          unsigned short* dst = (w == 0) ? qbf : kbf;
          const float sc = (w == 0) ? QSCALE : 1.0f;
          const int kc = d >> 4, l5 = (d >> 3) & 1, e = d & 7;
          const size_t basei =
              ((((size_t)bh * 32 + tb) * 2 + kh) * 4 + kc) * 512 + (size_t)l5 * 256 + e;
          const int r0 = (s0 & 31) * 8;
#pragma unroll
          for (int r = 0; r < 4; r++)
            dst[basei + r0 + r * 8] = f2bf_fast((acc[i][j][r] + bb) * sc);
        }
      }
    }
  }
}

// ---------------------------------------------------------------------------
// Kernel 3: flash attention. S^T = K·Q^T (bf16 mfma), O^T = V^T·P^T and
// l = ones·P^T (fp16 mfma; P via packed v_cvt_pkrtz). Block = 32 q-rows of
// one head; 4 waves each own a 32-key slice of a 128-key tile (4-way key
// split -> 2x wave parallelism vs R6), combined once through LDS at the end.
// All operand loads are fragment-swizzled (base + lane*8, coalesced).
// Grid 1536 (24 bh x 64 q-tiles), XCD-swizzled.
// ---------------------------------------------------------------------------
#define PROW 40   // P^T row stride in halves (80 B)

__global__ __launch_bounds__(256, 4) void attn_kernel(
    const unsigned short* __restrict__ qb, const unsigned short* __restrict__ kb,
    const _Float16* __restrict__ vth, unsigned short* __restrict__ ao) {
  // union: Ps (10 KB, K-loop) / C1+C2 combine buffers (25.5 KB, epilogue)
  __shared__ __align__(16) unsigned char smem[26112];
  _Float16* Ps = (_Float16*)smem;
  float* C1 = (float*)smem;        // [3][64][17] : oacc0 + l from waves 1,2,3
  float* C2 = C1 + 3 * 64 * 17;    // [3][64][17] : oacc1 + l from waves 0,2,3

  const int t = threadIdx.x;
  const int lane = t & 63, wv = t >> 6;
  const int l31 = lane & 31, l5 = lane >> 5;

  // XCD swizzle: id%8 = XCD -> 3 heads per XCD stay L2-resident
  const int id = blockIdx.x;
  const int bh = (id & 7) * 3 + ((id >> 3) >> 6);
  const int qt = (id >> 3) & 63;
  const int b = bh / H_, h = bh % H_;
  const int q0 = qt * 32;

  // Q fragments (B-operand, 32 q-rows), resident
  short8 qf[4];
  {
    const unsigned short* qp =
        qb + ((size_t)(bh * 32 + (qt >> 1)) * 2 + (qt & 1)) * 2048 + (size_t)lane * 8;
#pragma unroll
    for (int kc = 0; kc < 4; kc++) qf[kc] = *(const short8*)(qp + kc * 512);
  }
  half8 ones;
#pragma unroll
  for (int i = 0; i < 8; i++) ones[i] = (_Float16)1.0f;

  floatx16 oacc0 = (floatx16)0.0f;   // O^T d 0..31 (partial: this wave's keys)
  floatx16 oacc1 = (floatx16)0.0f;   // O^T d 32..63
  floatx16 lacc  = (floatx16)0.0f;   // partial softmax denominator

  // this wave's key slice: 64-block index (wv>>1), half (wv&1); tile stride 8192
  const unsigned short* kpb =
      kb + (size_t)(bh * 32 + (wv >> 1)) * 4096 + (size_t)(wv & 1) * 2048 + (size_t)lane * 8;
  const _Float16* vpb =
      vth + (size_t)(bh * 32 + (wv >> 1)) * 4096 + (size_t)(wv & 1) * 2048 + (size_t)lane * 8;
  _Float16* PsW = Ps + wv * 32 * PROW;

  short8 kf[4];
#pragma unroll
  for (int kc = 0; kc < 4; kc++) kf[kc] = *(const short8*)(kpb + kc * 512);

  for (int tb = 0; tb < 16; tb++) {
    const _Float16* vt = vpb + (size_t)tb * 8192;
    half8 vf0 = *(const half8*)(vt);            // d 0..31,  keys 0..15
    half8 vf1 = *(const half8*)(vt + 512);      // d 0..31,  keys 16..31
    half8 vf2 = *(const half8*)(vt + 1024);     // d 32..63, keys 0..15
    half8 vf3 = *(const half8*)(vt + 1536);     // d 32..63, keys 16..31

    // ---- S^T = K Q^T (row = key = (reg&3)+8*(reg>>2)+4*l5, col = q = l31)
    floatx16 sacc = (floatx16)0.0f;
#pragma unroll
    for (int kc = 0; kc < 4; kc++)
      sacc = __builtin_amdgcn_mfma_f32_32x32x16_bf16(kf[kc], qf[kc], sacc, 0, 0, 0);

    // prefetch next tile's K frags
    {
      const unsigned short* kt = kpb + (size_t)((tb + 1) & 15) * 8192;
#pragma unroll
      for (int kc = 0; kc < 4; kc++) kf[kc] = *(const short8*)(kt + kc * 512);
    }

    // ---- p = exp2(s); packed fp16 cvt; write P^T rows (wave-private)
#pragma unroll
    for (int r = 0; r < 16; r++) sacc[r] = exp2f(sacc[r]);
#pragma unroll
    for (int rq = 0; rq < 4; rq++) {
      half2_t a = pkrtz(sacc[rq * 4 + 0], sacc[rq * 4 + 1]);
      half2_t c = pkrtz(sacc[rq * 4 + 2], sacc[rq * 4 + 3]);
      half4 w = __builtin_shufflevector(a, c, 0, 1, 2, 3);
      *(half4*)&PsW[l31 * PROW + rq * 8 + l5 * 4] = w;   // keys 8rq+4l5..+3
    }

    // ---- read P^T as B-operand; same-wave DS ordering, no barrier
    const _Float16* prd = &PsW[l31 * PROW + l5 * 8];
    half8 pf0 = *(const half8*)(prd);        // keys  0..15
    half8 pf1 = *(const half8*)(prd + 16);   // keys 16..31

    // ---- O^T += V^T P^T ;  l += ones·P^T   (fp16 MFMA)
    oacc0 = __builtin_amdgcn_mfma_f32_32x32x16_f16(vf0, pf0, oacc0, 0, 0, 0);
    oacc0 = __builtin_amdgcn_mfma_f32_32x32x16_f16(vf1, pf1, oacc0, 0, 0, 0);
    oacc1 = __builtin_amdgcn_mfma_f32_32x32x16_f16(vf2, pf0, oacc1, 0, 0, 0);
    oacc1 = __builtin_amdgcn_mfma_f32_32x32x16_f16(vf3, pf1, oacc1, 0, 0, 0);
    lacc  = __builtin_amdgcn_mfma_f32_32x32x16_f16(ones, pf0, lacc, 0, 0, 0);
    lacc  = __builtin_amdgcn_mfma_f32_32x32x16_f16(ones, pf1, lacc, 0, 0, 0);
  }

  // ---- 4-way key combine (linear in keys), normalize, store
  __syncthreads();  // all P reads done before overwriting Ps with C1/C2
  if (wv > 0) {
    float* c = &C1[(size_t)((wv - 1) * 64 + lane) * 17];
#pragma unroll
    for (int j = 0; j < 16; j++) c[j] = oacc0[j];
    c[16] = lacc[0];
  }
  if (wv != 1) {
    const int slot = (wv == 0) ? 0 : wv - 1;
    float* c = &C2[(size_t)(slot * 64 + lane) * 17];
#pragma unroll
    for (int j = 0; j < 16; j++) c[j] = oacc1[j];
    c[16] = lacc[0];
  }
  __syncthreads();
  if (wv < 2) {
    float o[16];
    float L;
    if (wv == 0) {
      L = lacc[0];
#pragma unroll
      for (int j = 0; j < 16; j++) o[j] = oacc0[j];
#pragma unroll
      for (int i = 0; i < 3; i++) {
        const float* c = &C1[(size_t)(i * 64 + lane) * 17];
#pragma unroll
        for (int j = 0; j < 16; j++) o[j] += c[j];
        L += c[16];
      }
    } else {
      L = lacc[0];
#pragma unroll
      for (int j = 0; j < 16; j++) o[j] = oacc1[j];
#pragma unroll
      for (int i = 0; i < 3; i++) {
        const float* c = &C2[(size_t)(i * 64 + lane) * 17];
#pragma unroll
        for (int j = 0; j < 16; j++) o[j] += c[j];
        L += c[16];
      }
    }
    const float inv = 1.0f / L;
    const int row = q0 + l31;
    const int dbase = wv * 32;  // wave 0 -> d 0..31, wave 1 -> d 32..63
    unsigned short* arow = &ao[((size_t)(b * S_ + row)) * E_ + h * HD_ + dbase];
#pragma unroll
    for (int a = 0; a < 4; a++) {
      ushort4 s;
      s.x = f2bf(o[a * 4 + 0] * inv);
      s.y = f2bf(o[a * 4 + 1] * inv);
      s.z = f2bf(o[a * 4 + 2] * inv);
      s.w = f2bf(o[a * 4 + 3] * inv);
      // d = 8a + 4*l5 + 0..3
      *(ushort4*)&arow[8 * a + 4 * l5] = s;
    }
  }
}

// ---------------------------------------------------------------------------
extern "C" void kernel_launch(void* const* d_in, const int* in_sizes, int n_in,
                              void* d_out, int out_size, void* d_ws, size_t ws_size,
                              hipStream_t stream) {
  const float* x     = (const float*)d_in[0];
  const float* gamma = (const float*)d_in[1];
  const float* beta  = (const float*)d_in[2];
  const float* Wqkv  = (const float*)d_in[3];
  const float* bqkv  = (const float*)d_in[4];
  const float* Wo    = (const float*)d_in[5];
  const float* bo    = (const float*)d_in[6];
  float* out = (float*)d_out;

  const size_t SZ = (size_t)M_ * E_;
  unsigned short* xnb = (unsigned short*)d_ws;
  unsigned short* qbf = xnb + SZ;
  unsigned short* kbf = qbf + SZ;
  _Float16*       vth = (_Float16*)(kbf + SZ);
  unsigned short* aob = (unsigned short*)(vth + SZ);
  unsigned short* wqb = aob + SZ;
  unsigned short* wob = wqb + (size_t)N3E * E_;

  const int nq4 = (N3E * E_) / 4;
  const int no4 = (E_ * E_) / 4;
  cvt_kernel<<<(nq4 + 255) / 256, 256, 0, stream>>>(Wqkv, wqb, nq4);
  cvt_kernel<<<(no4 + 255) / 256, 256, 0, stream>>>(Wo, wob, no4);

  ln_kernel<<<M_, 256, 0, stream>>>(x, gamma, beta, xnb);

  dim3 g_qkv(M_ / 128, N3E / 128);  // (32, 18)
  bgemm_kernel<<<g_qkv, 256, 0, stream>>>(xnb, wqb, bqkv, 0, qbf, kbf, vth, nullptr);

  attn_kernel<<<1536, 256, 0, stream>>>(qbf, kbf, vth, aob);

  dim3 g_out(M_ / 128, E_ / 128);   // (32, 6)
  bgemm_kernel<<<g_out, 256, 0, stream>>>(aob, wob, bo, 1, nullptr, nullptr, nullptr, out);
}

// Round 9
// 182.704 us; speedup vs baseline: 1.0570x; 1.0570x over previous
//
#include <hip/hip_runtime.h>
#include <math.h>

// Problem constants
#define B_  2
#define S_  2048
#define E_  768
#define H_  12
#define HD_ 64
#define M_  (B_ * S_)     // 4096 rows
#define N3E (3 * E_)      // 2304

typedef __attribute__((ext_vector_type(8)))  short short8;      // 8 bf16
typedef __attribute__((ext_vector_type(8)))  _Float16 half8;    // 8 fp16
typedef __attribute__((ext_vector_type(4)))  _Float16 half4;
typedef __attribute__((ext_vector_type(2)))  _Float16 half2_t;
typedef __attribute__((ext_vector_type(4)))  float floatx4;     // 16x16 MFMA C/D
typedef __attribute__((ext_vector_type(16))) float floatx16;    // 32x32 MFMA C/D

// fold 1/sqrt(64) * log2(e) into q so softmax is a bare v_exp_f32 (exp2)
#define QSCALE 0.18033688011112042f

// round-to-nearest-even fp32 -> bf16
__device__ inline unsigned short f2bf(float f) {
  union { float f; unsigned u; } a; a.f = f;
  unsigned r = a.u + 0x7fff + ((a.u >> 16) & 1);
  return (unsigned short)(r >> 16);
}
// round-half-up (2 VALU ops; still <= 0.5 ulp)
__device__ inline unsigned short f2bf_fast(float f) {
  union { float f; unsigned u; } a; a.f = f;
  return (unsigned short)((a.u + 0x8000u) >> 16);
}
// packed fp32x2 -> fp16x2 (single v_cvt_pkrtz_f16_f32)
__device__ inline half2_t pkrtz(float a, float b) {
  return __builtin_bit_cast(half2_t, __builtin_amdgcn_cvt_pkrtz(a, b));
}

// ---------------------------------------------------------------------------
// Kernel 0: fp32 -> bf16 conversion of BOTH weight matrices in one launch
// ---------------------------------------------------------------------------
__global__ __launch_bounds__(256) void cvt2_kernel(
    const float* __restrict__ w1, const float* __restrict__ w2,
    unsigned short* __restrict__ d1, unsigned short* __restrict__ d2,
    int n1_4, int ntot4) {
  int i = blockIdx.x * 256 + threadIdx.x;
  if (i >= ntot4) return;
  const float* src; unsigned short* dst; int k;
  if (i < n1_4) { src = w1; dst = d1; k = i; }
  else          { src = w2; dst = d2; k = i - n1_4; }
  float4 f = *(const float4*)&src[k * 4];
  ushort4 r;
  r.x = f2bf(f.x); r.y = f2bf(f.y); r.z = f2bf(f.z); r.w = f2bf(f.w);
  *(ushort4*)&dst[k * 4] = r;
}

// ---------------------------------------------------------------------------
// Kernel 1: LayerNorm -> bf16 xn. One wave per row: float4 loads, pure
// shuffle reduction (no LDS, no barrier). Grid M_/4 blocks x 256.
// ---------------------------------------------------------------------------
__global__ __launch_bounds__(256) void ln_kernel(
    const float* __restrict__ x, const float* __restrict__ gamma,
    const float* __restrict__ beta, unsigned short* __restrict__ xnb) {
  const int wv = threadIdx.x >> 6, lane = threadIdx.x & 63;
  const int row = blockIdx.x * 4 + wv;
  const float* xr = x + (size_t)row * E_;

  float4 a = ((const float4*)xr)[lane];
  float4 b = ((const float4*)xr)[lane + 64];
  float4 c = ((const float4*)xr)[lane + 128];

  float s  = (a.x + a.y) + (a.z + a.w) + (b.x + b.y) + (b.z + b.w)
           + (c.x + c.y) + (c.z + c.w);
  float s2 = a.x*a.x + a.y*a.y + a.z*a.z + a.w*a.w
           + b.x*b.x + b.y*b.y + b.z*b.z + b.w*b.w
           + c.x*c.x + c.y*c.y + c.z*c.z + c.w*c.w;
#pragma unroll
  for (int o = 32; o > 0; o >>= 1) {
    s  += __shfl_xor(s, o);
    s2 += __shfl_xor(s2, o);
  }
  const float mu  = s * (1.0f / E_);
  const float var = s2 * (1.0f / E_) - mu * mu;
  const float rs  = rsqrtf(var + 1e-5f);

  const float4* gp = (const float4*)gamma;
  const float4* bp = (const float4*)beta;
  ushort4* xo = (ushort4*)(xnb + (size_t)row * E_);

  float4 vin[3] = {a, b, c};
#pragma unroll
  for (int j = 0; j < 3; j++) {
    float4 g = gp[lane + 64 * j];
    float4 be = bp[lane + 64 * j];
    float4 v = vin[j];
    ushort4 r;
    r.x = f2bf((v.x - mu) * rs * g.x + be.x);
    r.y = f2bf((v.y - mu) * rs * g.y + be.y);
    r.z = f2bf((v.z - mu) * rs * g.z + be.z);
    r.w = f2bf((v.w - mu) * rs * g.w + be.w);
    xo[lane + 64 * j] = r;
  }
}

// ---------------------------------------------------------------------------
// Kernel 2/4: bf16 MFMA GEMM  C[M][N] = A[M][768] * W[N][768]^T + bias[N]
// mode 0 epilogue emits q/k (bf16) and v (fp16) in MFMA-fragment-swizzled
// layouts so attention fragment loads are base + lane*8 (fully coalesced):
//   q/k: [bh][tb64][half][kc][lane][8]   (q pre-scaled by QSCALE)
//   v:   [bh][tb64][half][db][kc2][lane][8]  (fp16)
// mode 1: fp32 out[M][768] = C + bias
// ---------------------------------------------------------------------------
__global__ __launch_bounds__(256) void bgemm_kernel(
    const unsigned short* __restrict__ A, const unsigned short* __restrict__ Wb,
    const float* __restrict__ bias, int mode,
    unsigned short* __restrict__ qbf, unsigned short* __restrict__ kbf,
    _Float16* __restrict__ vth, float* __restrict__ out) {
  __shared__ __align__(16) unsigned short As[128 * 64];
  __shared__ __align__(16) unsigned short Bs[128 * 64];

  const int t  = threadIdx.x;
  const int ln = t & 63, wv = t >> 6;
  const int lr = ln & 15, lg = ln >> 4;
  const int wr = wv >> 1, wc = wv & 1;
  const int m0 = blockIdx.x * 128, n0 = blockIdx.y * 128;

  const int srow = ln >> 3;
  const int scol = (ln & 7) * 8;

  const unsigned short* Ag = A  + (size_t)(m0 + wv * 32 + srow) * 768 + scol;
  const unsigned short* Bg = Wb + (size_t)(n0 + wv * 32 + srow) * 768 + scol;

  floatx4 acc[4][4];
#pragma unroll
  for (int i = 0; i < 4; i++)
#pragma unroll
    for (int j = 0; j < 4; j++) acc[i][j] = (floatx4){0.f, 0.f, 0.f, 0.f};

  for (int k0 = 0; k0 < 768; k0 += 64) {
    __syncthreads();
#pragma unroll
    for (int j = 0; j < 4; j++) {
      __builtin_amdgcn_global_load_lds(
          (const __attribute__((address_space(1))) void*)(Ag + k0 + j * 8 * 768),
          (__attribute__((address_space(3))) void*)(&As[(wv * 32 + j * 8) * 64]),
          16, 0, 0);
      __builtin_amdgcn_global_load_lds(
          (const __attribute__((address_space(1))) void*)(Bg + k0 + j * 8 * 768),
          (__attribute__((address_space(3))) void*)(&Bs[(wv * 32 + j * 8) * 64]),
          16, 0, 0);
    }
    __syncthreads();

#pragma unroll
    for (int kk = 0; kk < 2; kk++) {
      short8 af[4], bf[4];
#pragma unroll
      for (int i = 0; i < 4; i++)
        af[i] = *(const short8*)&As[(wr * 64 + i * 16 + lr) * 64 + kk * 32 + lg * 8];
#pragma unroll
      for (int j = 0; j < 4; j++)
        bf[j] = *(const short8*)&Bs[(wc * 64 + j * 16 + lr) * 64 + kk * 32 + lg * 8];
#pragma unroll
      for (int i = 0; i < 4; i++)
#pragma unroll
        for (int j = 0; j < 4; j++)
          acc[i][j] = __builtin_amdgcn_mfma_f32_16x16x32_bf16(af[i], bf[j], acc[i][j], 0, 0, 0);
    }
  }

  if (mode == 1) {
#pragma unroll
    for (int i = 0; i < 4; i++) {
      const int grow0 = m0 + wr * 64 + i * 16 + lg * 4;
#pragma unroll
      for (int j = 0; j < 4; j++) {
        const int gcol = n0 + wc * 64 + j * 16 + lr;
        const float bb = bias[gcol];
#pragma unroll
        for (int r = 0; r < 4; r++)
          out[(size_t)(grow0 + r) * E_ + gcol] = acc[i][j][r] + bb;
      }
    }
  } else {
#pragma unroll
    for (int i = 0; i < 4; i++) {
      const int grow0 = m0 + wr * 64 + i * 16 + lg * 4;
      const int bq = grow0 >> 11, s0 = grow0 & 2047;
      const int tb = s0 >> 6, kh = (s0 >> 5) & 1;
#pragma unroll
      for (int j = 0; j < 4; j++) {
        const int n = n0 + wc * 64 + j * 16 + lr;
        const int h = n / 192, w = (n >> 6) % 3, d = n & 63;
        const int bh = bq * H_ + h;
        const float bb = bias[n];
        if (w == 2) {
          // V fragment layout (fp16): rows = keys s0..s0+3 -> e0..e0+3
          const int db = d >> 5, l31v = d & 31;
          const int kc2 = (s0 >> 4) & 1, l5v = (s0 >> 3) & 1, e0 = s0 & 7;
          half2_t h01 = pkrtz(acc[i][j][0] + bb, acc[i][j][1] + bb);
          half2_t h23 = pkrtz(acc[i][j][2] + bb, acc[i][j][3] + bb);
          half4 hv = __builtin_shufflevector(h01, h23, 0, 1, 2, 3);
          const size_t idx =
              ((((((size_t)bh * 32 + tb) * 2 + kh) * 2 + db) * 2 + kc2) * 2 + l5v) * 256
              + (size_t)l31v * 8 + e0;
          *(half4*)&vth[idx] = hv;
        } else {
          unsigned short* dst = (w == 0) ? qbf : kbf;
          const float sc = (w == 0) ? QSCALE : 1.0f;
          const int kc = d >> 4, l5 = (d >> 3) & 1, e = d & 7;
          const size_t basei =
              ((((size_t)bh * 32 + tb) * 2 + kh) * 4 + kc) * 512 + (size_t)l5 * 256 + e;
          const int r0 = (s0 & 31) * 8;
#pragma unroll
          for (int r = 0; r < 4; r++)
            dst[basei + r0 + r * 8] = f2bf_fast((acc[i][j][r] + bb) * sc);
        }
      }
    }
  }
}

// ---------------------------------------------------------------------------
// Kernel 3: flash attention, software-pipelined.
//   S^T = K·Q^T (bf16 mfma), O^T = V^T·P^T (fp16 mfma).
// Pipeline per tile t: exp/pack(t) [VALU] overlaps PV(t-1)+QK(t) [MFMA];
// K prefetch distance 2, V distance 1, single-buffered (load after last use).
// l is a per-lane scalar (all 16 scores share q=l31): VALU tree-sum, no MFMA.
// 4 waves each own a 32-key slice of a 128-key tile; combined via LDS.
// Grid 1536 (24 bh x 64 q-tiles of 32 rows), XCD-swizzled.
// ---------------------------------------------------------------------------
#define PROW 40   // P^T row stride in halves (80 B)

__global__ __launch_bounds__(256, 4) void attn_kernel(
    const unsigned short* __restrict__ qb, const unsigned short* __restrict__ kb,
    const _Float16* __restrict__ vth, unsigned short* __restrict__ ao) {
  // union: Ps (10 KB, K-loop) / C1+C2 combine buffers (25.5 KB, epilogue)
  __shared__ __align__(16) unsigned char smem[26112];
  _Float16* Ps = (_Float16*)smem;
  float* C1 = (float*)smem;        // [3][64][17] : oacc0 + l from waves 1,2,3
  float* C2 = C1 + 3 * 64 * 17;    // [3][64][17] : oacc1 + l from waves 0,2,3

  const int t = threadIdx.x;
  const int lane = t & 63, wv = t >> 6;
  const int l31 = lane & 31, l5 = lane >> 5;

  // XCD swizzle: id%8 = XCD -> 3 heads per XCD stay L2-resident
  const int id = blockIdx.x;
  const int bh = (id & 7) * 3 + ((id >> 3) >> 6);
  const int qt = (id >> 3) & 63;
  const int b = bh / H_, h = bh % H_;
  const int q0 = qt * 32;

  // Q fragments (B-operand, 32 q-rows), resident
  short8 qf[4];
  {
    const unsigned short* qp =
        qb + ((size_t)(bh * 32 + (qt >> 1)) * 2 + (qt & 1)) * 2048 + (size_t)lane * 8;
#pragma unroll
    for (int kc = 0; kc < 4; kc++) qf[kc] = *(const short8*)(qp + kc * 512);
  }

  floatx16 oacc0 = (floatx16)0.0f;   // O^T d 0..31 (partial: this wave's keys)
  floatx16 oacc1 = (floatx16)0.0f;   // O^T d 32..63
  float lsum = 0.f;                  // partial denominator for q = l31

  // this wave's key slice: 64-block (wv>>1), half (wv&1); tile stride 8192
  const unsigned short* kpb =
      kb + (size_t)(bh * 32 + (wv >> 1)) * 4096 + (size_t)(wv & 1) * 2048 + (size_t)lane * 8;
  const _Float16* vpb =
      vth + (size_t)(bh * 32 + (wv >> 1)) * 4096 + (size_t)(wv & 1) * 2048 + (size_t)lane * 8;
  _Float16* PsW = Ps + wv * 32 * PROW;

  // ---- prologue: K(0) -> S(0); then K(1), V(0) in flight
  short8 kf[4];
  half8 vf[4];
#pragma unroll
  for (int kc = 0; kc < 4; kc++) kf[kc] = *(const short8*)(kpb + kc * 512);
  floatx16 sacc = (floatx16)0.0f;
#pragma unroll
  for (int kc = 0; kc < 4; kc++)
    sacc = __builtin_amdgcn_mfma_f32_32x32x16_bf16(kf[kc], qf[kc], sacc, 0, 0, 0);
#pragma unroll
  for (int kc = 0; kc < 4; kc++) kf[kc] = *(const short8*)(kpb + 8192 + kc * 512);
#pragma unroll
  for (int j = 0; j < 4; j++) vf[j] = *(const half8*)(vpb + j * 512);

  for (int tb = 0; tb < 16; tb++) {
    // ---- exp(t) in place; l tree-sum (VALU; overlaps prior MFMA batch)
#pragma unroll
    for (int r = 0; r < 16; r++) sacc[r] = exp2f(sacc[r]);
    {
      float s01 = (sacc[0] + sacc[1]) + (sacc[2] + sacc[3]);
      float s23 = (sacc[4] + sacc[5]) + (sacc[6] + sacc[7]);
      float s45 = (sacc[8] + sacc[9]) + (sacc[10] + sacc[11]);
      float s67 = (sacc[12] + sacc[13]) + (sacc[14] + sacc[15]);
      lsum += (s01 + s23) + (s45 + s67);
    }
    // ---- pack to fp16, write P^T rows (wave-private LDS)
#pragma unroll
    for (int rq = 0; rq < 4; rq++) {
      half2_t a = pkrtz(sacc[rq * 4 + 0], sacc[rq * 4 + 1]);
      half2_t c = pkrtz(sacc[rq * 4 + 2], sacc[rq * 4 + 3]);
      half4 w = __builtin_shufflevector(a, c, 0, 1, 2, 3);
      *(half4*)&PsW[l31 * PROW + rq * 8 + l5 * 4] = w;   // keys 8rq+4l5..+3
    }
    // ---- read P^T as B-operand; same-wave DS ordering, no barrier
    const _Float16* prd = &PsW[l31 * PROW + l5 * 8];
    half8 pf0 = *(const half8*)(prd);        // keys  0..15
    half8 pf1 = *(const half8*)(prd + 16);   // keys 16..31

    // ---- PV(t)  (fp16 MFMA)
    oacc0 = __builtin_amdgcn_mfma_f32_32x32x16_f16(vf[0], pf0, oacc0, 0, 0, 0);
    oacc0 = __builtin_amdgcn_mfma_f32_32x32x16_f16(vf[1], pf1, oacc0, 0, 0, 0);
    oacc1 = __builtin_amdgcn_mfma_f32_32x32x16_f16(vf[2], pf0, oacc1, 0, 0, 0);
    oacc1 = __builtin_amdgcn_mfma_f32_32x32x16_f16(vf[3], pf1, oacc1, 0, 0, 0);

    if (tb != 15) {
      // ---- prefetch V(t+1) (distance 1: used by PV next iter)
      const _Float16* vt2 = vpb + (size_t)(tb + 1) * 8192;
#pragma unroll
      for (int j = 0; j < 4; j++) vf[j] = *(const half8*)(vt2 + j * 512);
      // ---- QK(t+1) into sacc (kf = K(t+1), prefetched at distance 2)
      sacc = (floatx16)0.0f;
#pragma unroll
      for (int kc = 0; kc < 4; kc++)
        sacc = __builtin_amdgcn_mfma_f32_32x32x16_bf16(kf[kc], qf[kc], sacc, 0, 0, 0);
      // ---- prefetch K(t+2)
      const unsigned short* kt2 = kpb + (size_t)((tb + 2) & 15) * 8192;
#pragma unroll
      for (int kc = 0; kc < 4; kc++) kf[kc] = *(const short8*)(kt2 + kc * 512);
    }
  }

  // ---- combine the two key-halves within this wave's l (l5 pair)
  const float l2 = lsum + __shfl_xor(lsum, 32);

  // ---- 4-way key combine across waves (linear), normalize, store
  __syncthreads();  // all P reads done before overwriting Ps with C1/C2
  if (wv > 0) {
    float* c = &C1[(size_t)((wv - 1) * 64 + lane) * 17];
#pragma unroll
    for (int j = 0; j < 16; j++) c[j] = oacc0[j];
    c[16] = l2;
  }
  if (wv != 1) {
    const int slot = (wv == 0) ? 0 : wv - 1;
    float* c = &C2[(size_t)(slot * 64 + lane) * 17];
#pragma unroll
    for (int j = 0; j < 16; j++) c[j] = oacc1[j];
    c[16] = l2;
  }
  __syncthreads();
  if (wv < 2) {
    float o[16];
    float L;
    if (wv == 0) {
      L = l2;
#pragma unroll
      for (int j = 0; j < 16; j++) o[j] = oacc0[j];
#pragma unroll
      for (int i = 0; i < 3; i++) {
        const float* c = &C1[(size_t)(i * 64 + lane) * 17];
#pragma unroll
        for (int j = 0; j < 16; j++) o[j] += c[j];
        L += c[16];
      }
    } else {
      L = l2;
#pragma unroll
      for (int j = 0; j < 16; j++) o[j] = oacc1[j];
#pragma unroll
      for (int i = 0; i < 3; i++) {
        const float* c = &C2[(size_t)(i * 64 + lane) * 17];
#pragma unroll
        for (int j = 0; j < 16; j++) o[j] += c[j];
        L += c[16];
      }
    }
    const float inv = 1.0f / L;
    const int row = q0 + l31;
    const int dbase = wv * 32;  // wave 0 -> d 0..31, wave 1 -> d 32..63
    unsigned short* arow = &ao[((size_t)(b * S_ + row)) * E_ + h * HD_ + dbase];
#pragma unroll
    for (int a = 0; a < 4; a++) {
      ushort4 s;
      s.x = f2bf(o[a * 4 + 0] * inv);
      s.y = f2bf(o[a * 4 + 1] * inv);
      s.z = f2bf(o[a * 4 + 2] * inv);
      s.w = f2bf(o[a * 4 + 3] * inv);
      // d = 8a + 4*l5 + 0..3
      *(ushort4*)&arow[8 * a + 4 * l5] = s;
    }
  }
}

// ---------------------------------------------------------------------------
extern "C" void kernel_launch(void* const* d_in, const int* in_sizes, int n_in,
                              void* d_out, int out_size, void* d_ws, size_t ws_size,
                              hipStream_t stream) {
  const float* x     = (const float*)d_in[0];
  const float* gamma = (const float*)d_in[1];
  const float* beta  = (const float*)d_in[2];
  const float* Wqkv  = (const float*)d_in[3];
  const float* bqkv  = (const float*)d_in[4];
  const float* Wo    = (const float*)d_in[5];
  const float* bo    = (const float*)d_in[6];
  float* out = (float*)d_out;

  const size_t SZ = (size_t)M_ * E_;
  unsigned short* xnb = (unsigned short*)d_ws;
  unsigned short* qbf = xnb + SZ;
  unsigned short* kbf = qbf + SZ;
  _Float16*       vth = (_Float16*)(kbf + SZ);
  unsigned short* aob = (unsigned short*)(vth + SZ);
  unsigned short* wqb = aob + SZ;
  unsigned short* wob = wqb + (size_t)N3E * E_;

  const int nq4 = (N3E * E_) / 4;   // 442368
  const int no4 = (E_ * E_) / 4;    // 147456
  const int ntot4 = nq4 + no4;
  cvt2_kernel<<<(ntot4 + 255) / 256, 256, 0, stream>>>(Wqkv, Wo, wqb, wob, nq4, ntot4);

  ln_kernel<<<M_ / 4, 256, 0, stream>>>(x, gamma, beta, xnb);

  dim3 g_qkv(M_ / 128, N3E / 128);  // (32, 18)
  bgemm_kernel<<<g_qkv, 256, 0, stream>>>(xnb, wqb, bqkv, 0, qbf, kbf, vth, nullptr);

  attn_kernel<<<1536, 256, 0, stream>>>(qbf, kbf, vth, aob);

  dim3 g_out(M_ / 128, E_ / 128);   // (32, 6)
  bgemm_kernel<<<g_out, 256, 0, stream>>>(aob, wob, bo, 1, nullptr, nullptr, nullptr, out);
}

// Round 10
// 175.109 us; speedup vs baseline: 1.1028x; 1.0434x over previous
//
#include <hip/hip_runtime.h>
#include <math.h>

// Problem constants
#define B_  2
#define S_  2048
#define E_  768
#define H_  12
#define HD_ 64
#define M_  (B_ * S_)     // 4096 rows
#define N3E (3 * E_)      // 2304

typedef __attribute__((ext_vector_type(8)))  short short8;      // 8 bf16
typedef __attribute__((ext_vector_type(4)))  short short4v;     // 4 bf16 (b64)
typedef __attribute__((ext_vector_type(8)))  _Float16 half8;    // 8 fp16
typedef __attribute__((ext_vector_type(4)))  _Float16 half4;
typedef __attribute__((ext_vector_type(2)))  _Float16 half2_t;
typedef __attribute__((ext_vector_type(4)))  float floatx4;     // 16x16 MFMA C/D
typedef __attribute__((ext_vector_type(16))) float floatx16;    // 32x32 MFMA C/D

// fold 1/sqrt(64) * log2(e) into q so softmax is a bare v_exp_f32 (exp2)
#define QSCALE 0.18033688011112042f

// round-to-nearest-even fp32 -> bf16
__device__ inline unsigned short f2bf(float f) {
  union { float f; unsigned u; } a; a.f = f;
  unsigned r = a.u + 0x7fff + ((a.u >> 16) & 1);
  return (unsigned short)(r >> 16);
}
// round-half-up (2 VALU ops; still <= 0.5 ulp)
__device__ inline unsigned short f2bf_fast(float f) {
  union { float f; unsigned u; } a; a.f = f;
  return (unsigned short)((a.u + 0x8000u) >> 16);
}
// packed fp32x2 -> fp16x2 (single v_cvt_pkrtz_f16_f32)
__device__ inline half2_t pkrtz(float a, float b) {
  return __builtin_bit_cast(half2_t, __builtin_amdgcn_cvt_pkrtz(a, b));
}

// ---------------------------------------------------------------------------
// Kernel 0: fp32 -> bf16 conversion of BOTH weight matrices in one launch
// ---------------------------------------------------------------------------
__global__ __launch_bounds__(256) void cvt2_kernel(
    const float* __restrict__ w1, const float* __restrict__ w2,
    unsigned short* __restrict__ d1, unsigned short* __restrict__ d2,
    int n1_4, int ntot4) {
  int i = blockIdx.x * 256 + threadIdx.x;
  if (i >= ntot4) return;
  const float* src; unsigned short* dst; int k;
  if (i < n1_4) { src = w1; dst = d1; k = i; }
  else          { src = w2; dst = d2; k = i - n1_4; }
  float4 f = *(const float4*)&src[k * 4];
  ushort4 r;
  r.x = f2bf(f.x); r.y = f2bf(f.y); r.z = f2bf(f.z); r.w = f2bf(f.w);
  *(ushort4*)&dst[k * 4] = r;
}

// ---------------------------------------------------------------------------
// Kernel 1: LayerNorm -> bf16 xn. One wave per row: float4 loads, pure
// shuffle reduction (no LDS, no barrier). Grid M_/4 blocks x 256.
// ---------------------------------------------------------------------------
__global__ __launch_bounds__(256) void ln_kernel(
    const float* __restrict__ x, const float* __restrict__ gamma,
    const float* __restrict__ beta, unsigned short* __restrict__ xnb) {
  const int wv = threadIdx.x >> 6, lane = threadIdx.x & 63;
  const int row = blockIdx.x * 4 + wv;
  const float* xr = x + (size_t)row * E_;

  float4 a = ((const float4*)xr)[lane];
  float4 b = ((const float4*)xr)[lane + 64];
  float4 c = ((const float4*)xr)[lane + 128];

  float s  = (a.x + a.y) + (a.z + a.w) + (b.x + b.y) + (b.z + b.w)
           + (c.x + c.y) + (c.z + c.w);
  float s2 = a.x*a.x + a.y*a.y + a.z*a.z + a.w*a.w
           + b.x*b.x + b.y*b.y + b.z*b.z + b.w*b.w
           + c.x*c.x + c.y*c.y + c.z*c.z + c.w*c.w;
#pragma unroll
  for (int o = 32; o > 0; o >>= 1) {
    s  += __shfl_xor(s, o);
    s2 += __shfl_xor(s2, o);
  }
  const float mu  = s * (1.0f / E_);
  const float var = s2 * (1.0f / E_) - mu * mu;
  const float rs  = rsqrtf(var + 1e-5f);

  const float4* gp = (const float4*)gamma;
  const float4* bp = (const float4*)beta;
  ushort4* xo = (ushort4*)(xnb + (size_t)row * E_);

  float4 vin[3] = {a, b, c};
#pragma unroll
  for (int j = 0; j < 3; j++) {
    float4 g = gp[lane + 64 * j];
    float4 be = bp[lane + 64 * j];
    float4 v = vin[j];
    ushort4 r;
    r.x = f2bf((v.x - mu) * rs * g.x + be.x);
    r.y = f2bf((v.y - mu) * rs * g.y + be.y);
    r.z = f2bf((v.z - mu) * rs * g.z + be.z);
    r.w = f2bf((v.w - mu) * rs * g.w + be.w);
    xo[lane + 64 * j] = r;
  }
}

// ---------------------------------------------------------------------------
// Kernel 2/4: bf16 MFMA GEMM, 128x64 tiles (more blocks -> latency hiding).
// 4 waves, each computing 32(m) x 64(n) via 2x4 frags of 16x16x32.
// mode 0 (QKV): per-block n-range is exactly one q/k/v 64-d group.
//   q/k blocks use SWAPPED mfma(bf, af): C/D rows = d -> each thread owns
//   4 consecutive d = one coalesced ushort4 store in d-quad layout
//   [bh][s-tile32][q4=d>>2][lane=s&31][4]  (q pre-scaled by QSCALE).
//   v blocks use normal orientation -> half4 stores (s-quads), fp16 layout
//   [bh][tb64][kh][db][kc2][l5][lane=d&31][8].
// mode 1: fp32 out[M][768] = C + bias.
// ---------------------------------------------------------------------------
__global__ __launch_bounds__(256) void bgemm_kernel(
    const unsigned short* __restrict__ A, const unsigned short* __restrict__ Wb,
    const float* __restrict__ bias, int mode,
    unsigned short* __restrict__ qbf, unsigned short* __restrict__ kbf,
    _Float16* __restrict__ vth, float* __restrict__ out) {
  __shared__ __align__(16) unsigned short As[128 * 64];
  __shared__ __align__(16) unsigned short Bs[64 * 64];

  const int t  = threadIdx.x;
  const int ln = t & 63, wv = t >> 6;
  const int lr = ln & 15, lg = ln >> 4;
  const int m0 = blockIdx.x * 128, n0 = blockIdx.y * 64;
  const int w  = (mode == 1) ? 3 : ((n0 >> 6) % 3);

  const int srow = ln >> 3;          // 0..7
  const int scol = (ln & 7) * 8;     // k-offset

  const unsigned short* Ag = A  + (size_t)(m0 + wv * 32 + srow) * 768 + scol;
  const unsigned short* Bg = Wb + (size_t)(n0 + wv * 16 + srow) * 768 + scol;

  floatx4 acc[2][4];
#pragma unroll
  for (int i = 0; i < 2; i++)
#pragma unroll
    for (int j = 0; j < 4; j++) acc[i][j] = (floatx4){0.f, 0.f, 0.f, 0.f};

  for (int k0 = 0; k0 < 768; k0 += 64) {
    __syncthreads();
#pragma unroll
    for (int j = 0; j < 4; j++)
      __builtin_amdgcn_global_load_lds(
          (const __attribute__((address_space(1))) void*)(Ag + k0 + j * 8 * 768),
          (__attribute__((address_space(3))) void*)(&As[(wv * 32 + j * 8) * 64]),
          16, 0, 0);
#pragma unroll
    for (int j = 0; j < 2; j++)
      __builtin_amdgcn_global_load_lds(
          (const __attribute__((address_space(1))) void*)(Bg + k0 + j * 8 * 768),
          (__attribute__((address_space(3))) void*)(&Bs[(wv * 16 + j * 8) * 64]),
          16, 0, 0);
    __syncthreads();

#pragma unroll
    for (int kk = 0; kk < 2; kk++) {
      short8 af[2], bf[4];
#pragma unroll
      for (int i = 0; i < 2; i++)
        af[i] = *(const short8*)&As[(wv * 32 + i * 16 + lr) * 64 + kk * 32 + lg * 8];
#pragma unroll
      for (int j = 0; j < 4; j++)
        bf[j] = *(const short8*)&Bs[(j * 16 + lr) * 64 + kk * 32 + lg * 8];
      if (w < 2) {  // swapped: C/D rows = n(d), cols = m(s)
#pragma unroll
        for (int i = 0; i < 2; i++)
#pragma unroll
          for (int j = 0; j < 4; j++)
            acc[i][j] = __builtin_amdgcn_mfma_f32_16x16x32_bf16(bf[j], af[i], acc[i][j], 0, 0, 0);
      } else {      // normal: C/D rows = m(s), cols = n(d)
#pragma unroll
        for (int i = 0; i < 2; i++)
#pragma unroll
          for (int j = 0; j < 4; j++)
            acc[i][j] = __builtin_amdgcn_mfma_f32_16x16x32_bf16(af[i], bf[j], acc[i][j], 0, 0, 0);
      }
    }
  }

  if (mode == 1) {
#pragma unroll
    for (int i = 0; i < 2; i++) {
      const int grow0 = m0 + wv * 32 + i * 16 + lg * 4;
#pragma unroll
      for (int j = 0; j < 4; j++) {
        const int gcol = n0 + j * 16 + lr;
        const float bb = bias[gcol];
#pragma unroll
        for (int r = 0; r < 4; r++)
          out[(size_t)(grow0 + r) * E_ + gcol] = acc[i][j][r] + bb;
      }
    }
  } else if (w < 2) {
    // q/k: d-quad layout, coalesced ushort4 stores
    const int h = n0 / 192;
    const int bh = (m0 >> 11) * H_ + h;
    unsigned short* dst = (w == 0) ? qbf : kbf;
    const float sc = (w == 0) ? QSCALE : 1.0f;
#pragma unroll
    for (int i = 0; i < 2; i++) {
      const int s = (m0 & 2047) + wv * 32 + i * 16 + lr;
      const size_t rowb = (size_t)bh * 131072 + (size_t)(s >> 5) * 2048 + (s & 31) * 4;
#pragma unroll
      for (int j = 0; j < 4; j++) {
        float4 b4 = *(const float4*)&bias[n0 + j * 16 + lg * 4];
        ushort4 r;
        r.x = f2bf_fast((acc[i][j][0] + b4.x) * sc);
        r.y = f2bf_fast((acc[i][j][1] + b4.y) * sc);
        r.z = f2bf_fast((acc[i][j][2] + b4.z) * sc);
        r.w = f2bf_fast((acc[i][j][3] + b4.w) * sc);
        *(ushort4*)&dst[rowb + (size_t)(j * 4 + lg) * 128] = r;
      }
    }
  } else {
    // v: fp16 fragment layout (s-quads), half4 stores
    const int h = n0 / 192;
    const int bh = (m0 >> 11) * H_ + h;
#pragma unroll
    for (int i = 0; i < 2; i++) {
      const int s0 = (m0 & 2047) + wv * 32 + i * 16 + lg * 4;
      const int tb = s0 >> 6, kh = (s0 >> 5) & 1;
      const int kc2 = (s0 >> 4) & 1, l5v = (s0 >> 3) & 1, e0 = s0 & 7;
#pragma unroll
      for (int j = 0; j < 4; j++) {
        const int d = j * 16 + lr;
        const int db = d >> 5, l31v = d & 31;
        const float bb = bias[n0 + d];
        half2_t h01 = pkrtz(acc[i][j][0] + bb, acc[i][j][1] + bb);
        half2_t h23 = pkrtz(acc[i][j][2] + bb, acc[i][j][3] + bb);
        half4 hv = __builtin_shufflevector(h01, h23, 0, 1, 2, 3);
        const size_t idx =
            ((((((size_t)bh * 32 + tb) * 2 + kh) * 2 + db) * 2 + kc2) * 2 + l5v) * 256
            + (size_t)l31v * 8 + e0;
        *(half4*)&vth[idx] = hv;
      }
    }
  }
}

// ---------------------------------------------------------------------------
// Kernel 3: flash attention, software-pipelined (unchanged structure from R9).
// q/k now in d-quad layout -> frags assembled from two coalesced b64 loads.
// ---------------------------------------------------------------------------
#define PROW 40   // P^T row stride in halves (80 B)

__global__ __launch_bounds__(256, 4) void attn_kernel(
    const unsigned short* __restrict__ qb, const unsigned short* __restrict__ kb,
    const _Float16* __restrict__ vth, unsigned short* __restrict__ ao) {
  // union: Ps (10 KB, K-loop) / C1+C2 combine buffers (25.5 KB, epilogue)
  __shared__ __align__(16) unsigned char smem[26112];
  _Float16* Ps = (_Float16*)smem;
  float* C1 = (float*)smem;        // [3][64][17] : oacc0 + l from waves 1,2,3
  float* C2 = C1 + 3 * 64 * 17;    // [3][64][17] : oacc1 + l from waves 0,2,3

  const int t = threadIdx.x;
  const int lane = t & 63, wv = t >> 6;
  const int l31 = lane & 31, l5 = lane >> 5;

  // XCD swizzle: id%8 = XCD -> 3 heads per XCD stay L2-resident
  const int id = blockIdx.x;
  const int bh = (id & 7) * 3 + ((id >> 3) >> 6);
  const int qt = (id >> 3) & 63;
  const int b = bh / H_, h = bh % H_;
  const int q0 = qt * 32;

  // Q fragments (B-operand, 32 q-rows): two b64 loads per frag, coalesced
  short8 qf[4];
  {
    const unsigned short* qp = qb + (size_t)bh * 131072 + (size_t)qt * 2048 + l31 * 4;
#pragma unroll
    for (int kc = 0; kc < 4; kc++) {
      short4v a = *(const short4v*)(qp + (kc * 4 + l5 * 2) * 128);
      short4v b2 = *(const short4v*)(qp + (kc * 4 + l5 * 2) * 128 + 128);
      qf[kc] = __builtin_shufflevector(a, b2, 0, 1, 2, 3, 4, 5, 6, 7);
    }
  }

  floatx16 oacc0 = (floatx16)0.0f;   // O^T d 0..31 (partial: this wave's keys)
  floatx16 oacc1 = (floatx16)0.0f;   // O^T d 32..63
  float lsum = 0.f;                  // partial denominator for q = l31

  // this wave's key slice (32-key tiles): kt = 4*tb + 2*(wv>>1) + (wv&1)
  const unsigned short* kpb =
      kb + (size_t)bh * 131072 + (size_t)(2 * (wv >> 1) + (wv & 1)) * 2048 + l31 * 4;
  const _Float16* vpb =
      vth + (size_t)(bh * 32 + (wv >> 1)) * 4096 + (size_t)(wv & 1) * 2048 + (size_t)lane * 8;
  _Float16* PsW = Ps + wv * 32 * PROW;

#define LDK(kfv, tb2)                                                          \
  {                                                                            \
    const unsigned short* _p = kpb + (size_t)(tb2) * 8192;                     \
    _Pragma("unroll")                                                          \
    for (int kc = 0; kc < 4; kc++) {                                           \
      short4v _a = *(const short4v*)(_p + (kc * 4 + l5 * 2) * 128);            \
      short4v _b = *(const short4v*)(_p + (kc * 4 + l5 * 2) * 128 + 128);      \
      kfv[kc] = __builtin_shufflevector(_a, _b, 0, 1, 2, 3, 4, 5, 6, 7);       \
    }                                                                          \
  }

  // ---- prologue: K(0) -> S(0); then K(1), V(0) in flight
  short8 kf[4];
  half8 vf[4];
  LDK(kf, 0);
  floatx16 sacc = (floatx16)0.0f;
#pragma unroll
  for (int kc = 0; kc < 4; kc++)
    sacc = __builtin_amdgcn_mfma_f32_32x32x16_bf16(kf[kc], qf[kc], sacc, 0, 0, 0);
  LDK(kf, 1);
#pragma unroll
  for (int j = 0; j < 4; j++) vf[j] = *(const half8*)(vpb + j * 512);

  for (int tb = 0; tb < 16; tb++) {
    // ---- exp(t) in place; l tree-sum (VALU; overlaps prior MFMA batch)
#pragma unroll
    for (int r = 0; r < 16; r++) sacc[r] = exp2f(sacc[r]);
    {
      float s01 = (sacc[0] + sacc[1]) + (sacc[2] + sacc[3]);
      float s23 = (sacc[4] + sacc[5]) + (sacc[6] + sacc[7]);
      float s45 = (sacc[8] + sacc[9]) + (sacc[10] + sacc[11]);
      float s67 = (sacc[12] + sacc[13]) + (sacc[14] + sacc[15]);
      lsum += (s01 + s23) + (s45 + s67);
    }
    // ---- pack to fp16, write P^T rows (wave-private LDS)
#pragma unroll
    for (int rq = 0; rq < 4; rq++) {
      half2_t a = pkrtz(sacc[rq * 4 + 0], sacc[rq * 4 + 1]);
      half2_t c = pkrtz(sacc[rq * 4 + 2], sacc[rq * 4 + 3]);
      half4 w = __builtin_shufflevector(a, c, 0, 1, 2, 3);
      *(half4*)&PsW[l31 * PROW + rq * 8 + l5 * 4] = w;   // keys 8rq+4l5..+3
    }
    // ---- read P^T as B-operand; same-wave DS ordering, no barrier
    const _Float16* prd = &PsW[l31 * PROW + l5 * 8];
    half8 pf0 = *(const half8*)(prd);        // keys  0..15
    half8 pf1 = *(const half8*)(prd + 16);   // keys 16..31

    // ---- PV(t)  (fp16 MFMA)
    oacc0 = __builtin_amdgcn_mfma_f32_32x32x16_f16(vf[0], pf0, oacc0, 0, 0, 0);
    oacc0 = __builtin_amdgcn_mfma_f32_32x32x16_f16(vf[1], pf1, oacc0, 0, 0, 0);
    oacc1 = __builtin_amdgcn_mfma_f32_32x32x16_f16(vf[2], pf0, oacc1, 0, 0, 0);
    oacc1 = __builtin_amdgcn_mfma_f32_32x32x16_f16(vf[3], pf1, oacc1, 0, 0, 0);

    if (tb != 15) {
      // ---- prefetch V(t+1) (distance 1: used by PV next iter)
      const _Float16* vt2 = vpb + (size_t)(tb + 1) * 8192;
#pragma unroll
      for (int j = 0; j < 4; j++) vf[j] = *(const half8*)(vt2 + j * 512);
      // ---- QK(t+1) into sacc (kf = K(t+1), prefetched at distance 2)
      sacc = (floatx16)0.0f;
#pragma unroll
      for (int kc = 0; kc < 4; kc++)
        sacc = __builtin_amdgcn_mfma_f32_32x32x16_bf16(kf[kc], qf[kc], sacc, 0, 0, 0);
      // ---- prefetch K(t+2)
      LDK(kf, (tb + 2) & 15);
    }
  }

  // ---- combine the two key-halves within this wave's l (l5 pair)
  const float l2 = lsum + __shfl_xor(lsum, 32);

  // ---- 4-way key combine across waves (linear), normalize, store
  __syncthreads();  // all P reads done before overwriting Ps with C1/C2
  if (wv > 0) {
    float* c = &C1[(size_t)((wv - 1) * 64 + lane) * 17];
#pragma unroll
    for (int j = 0; j < 16; j++) c[j] = oacc0[j];
    c[16] = l2;
  }
  if (wv != 1) {
    const int slot = (wv == 0) ? 0 : wv - 1;
    float* c = &C2[(size_t)(slot * 64 + lane) * 17];
#pragma unroll
    for (int j = 0; j < 16; j++) c[j] = oacc1[j];
    c[16] = l2;
  }
  __syncthreads();
  if (wv < 2) {
    float o[16];
    float L;
    if (wv == 0) {
      L = l2;
#pragma unroll
      for (int j = 0; j < 16; j++) o[j] = oacc0[j];
#pragma unroll
      for (int i = 0; i < 3; i++) {
        const float* c = &C1[(size_t)(i * 64 + lane) * 17];
#pragma unroll
        for (int j = 0; j < 16; j++) o[j] += c[j];
        L += c[16];
      }
    } else {
      L = l2;
#pragma unroll
      for (int j = 0; j < 16; j++) o[j] = oacc1[j];
#pragma unroll
      for (int i = 0; i < 3; i++) {
        const float* c = &C2[(size_t)(i * 64 + lane) * 17];
#pragma unroll
        for (int j = 0; j < 16; j++) o[j] += c[j];
        L += c[16];
      }
    }
    const float inv = 1.0f / L;
    const int row = q0 + l31;
    const int dbase = wv * 32;  // wave 0 -> d 0..31, wave 1 -> d 32..63
    unsigned short* arow = &ao[((size_t)(b * S_ + row)) * E_ + h * HD_ + dbase];
#pragma unroll
    for (int a = 0; a < 4; a++) {
      ushort4 s;
      s.x = f2bf(o[a * 4 + 0] * inv);
      s.y = f2bf(o[a * 4 + 1] * inv);
      s.z = f2bf(o[a * 4 + 2] * inv);
      s.w = f2bf(o[a * 4 + 3] * inv);
      // d = 8a + 4*l5 + 0..3
      *(ushort4*)&arow[8 * a + 4 * l5] = s;
    }
  }
}

// ---------------------------------------------------------------------------
extern "C" void kernel_launch(void* const* d_in, const int* in_sizes, int n_in,
                              void* d_out, int out_size, void* d_ws, size_t ws_size,
                              hipStream_t stream) {
  const float* x     = (const float*)d_in[0];
  const float* gamma = (const float*)d_in[1];
  const float* beta  = (const float*)d_in[2];
  const float* Wqkv  = (const float*)d_in[3];
  const float* bqkv  = (const float*)d_in[4];
  const float* Wo    = (const float*)d_in[5];
  const float* bo    = (const float*)d_in[6];
  float* out = (float*)d_out;

  const size_t SZ = (size_t)M_ * E_;
  unsigned short* xnb = (unsigned short*)d_ws;
  unsigned short* qbf = xnb + SZ;
  unsigned short* kbf = qbf + SZ;
  _Float16*       vth = (_Float16*)(kbf + SZ);
  unsigned short* aob = (unsigned short*)(vth + SZ);
  unsigned short* wqb = aob + SZ;
  unsigned short* wob = wqb + (size_t)N3E * E_;

  const int nq4 = (N3E * E_) / 4;   // 442368
  const int no4 = (E_ * E_) / 4;    // 147456
  const int ntot4 = nq4 + no4;
  cvt2_kernel<<<(ntot4 + 255) / 256, 256, 0, stream>>>(Wqkv, Wo, wqb, wob, nq4, ntot4);

  ln_kernel<<<M_ / 4, 256, 0, stream>>>(x, gamma, beta, xnb);

  dim3 g_qkv(M_ / 128, N3E / 64);   // (32, 36) = 1152 blocks
  bgemm_kernel<<<g_qkv, 256, 0, stream>>>(xnb, wqb, bqkv, 0, qbf, kbf, vth, nullptr);

  attn_kernel<<<1536, 256, 0, stream>>>(qbf, kbf, vth, aob);

  dim3 g_out(M_ / 128, E_ / 64);    // (32, 12) = 384 blocks
  bgemm_kernel<<<g_out, 256, 0, stream>>>(aob, wob, bo, 1, nullptr, nullptr, nullptr, out);
}